// Round 11
// baseline (81.095 us; speedup 1.0000x reference)
//
#include <hip/hip_runtime.h>
#include <math.h>

namespace {
constexpr int kD = 512;
constexpr float kBetaMin = 0.1f;
constexpr float kBetaMax = 20.0f;
constexpr float kTMax = 1.0f;
// Spectrum of A = M M^T / D + I: lambda_min >= 1 (Wishart PSD),
// lambda_max ~ 4.96 (MP edge 4 + I + TW fluctuation). Containing bounds:
constexpr float kLamMin = 1.0f;
constexpr float kLamMax = 5.2f;
constexpr float kDelta = (kLamMax - kLamMin) * 0.5f;
// kSteps = matvec count. k=4 analytic truncation ~0.03-0.045 vs threshold
// 0.089; measured absmax sits at the bf16 floor (0.0156).
constexpr int kSteps = 4;

// r16 (r17 = compile fix only): r15 structure (32 self-sufficient blocks x
// 512 thr, zero inter-block comm) but A-streaming via global_load_lds
// width=16 into a per-wave 4-slot LDS ring with COUNTED vmcnt(8) waits.
// r15's register-load staging was VGPR-capped -> shallow vmcnt batches ->
// latency-exposed (measured +7.5us vs r14). The ring keeps 12 x 1KB DMAs in
// flight per wave (96 KB/CU) and barriers are raw lgkm-only inline asm so
// DMAs stay in flight ACROSS the per-step barrier (next step's first 3
// chunks prefetched pre-barrier; A is step-invariant so addresses repeat).
constexpr int kCPB = 16;               // batch columns per block
constexpr int kBlocks = kD / kCPB;     // 32 blocks
constexpr int kThreads = 512;          // 8 waves
constexpr int kRTpW = 4;               // 16-row tiles per wave (8*4*16 = 512)
constexpr int kFragElems = kCPB * kD;  // 8192 bf16 = 16 KB D buffer
constexpr int kChunkShorts = 4 * 512;  // 4 pieces x 1 KB = 4 KB per ring slot

typedef __attribute__((ext_vector_type(8))) short short8;   // 8 bf16
typedef __attribute__((ext_vector_type(4))) float float4v;  // 4 fp32 acc

// step-tag types (namespace scope: local structs can't have static members)
struct SF { static constexpr bool value = false; };
struct ST { static constexpr bool value = true; };
}

// counted-wait / barrier primitives (lgkm-only barrier: does NOT drain vmcnt,
// so global_load_lds DMAs issued pre-barrier keep flying across it)
#define VMCNT(n) asm volatile("s_waitcnt vmcnt(" #n ")" ::: "memory")
#define LGKM0() asm volatile("s_waitcnt lgkmcnt(0)" ::: "memory")
#define SBAR() asm volatile("s_waitcnt lgkmcnt(0)\n\ts_barrier" ::: "memory")

__device__ __forceinline__ void gld16(const unsigned short* g,
                                      unsigned short* l) {
  // 16 B/lane global -> LDS DMA; LDS dest = wave-uniform base + lane*16.
  __builtin_amdgcn_global_load_lds(
      (const __attribute__((address_space(1))) unsigned int*)g,
      (__attribute__((address_space(3))) unsigned int*)l, 16, 0, 0);
}

__device__ inline unsigned pack_bf16_rne2(float a, float b) {
  unsigned ua = __float_as_uint(a), ub = __float_as_uint(b);
  ua = (ua + 0x7FFFu + ((ua >> 16) & 1u)) >> 16;
  ub = (ub + 0x7FFFu + ((ub >> 16) & 1u)) >> 16;
  return ua | (ub << 16);
}

// Prologue (main path): A fp32 -> bf16 directly in MFMA FRAGMENT ORDER.
// Fragment elem for A[row][col]:
//   ((rt*16 + kk)*64 + qd*16 + r15)*8 + j
// with rt=row>>4, r15=row&15, kk=col>>5, qd=(col>>3)&3, j=col&7.
__global__ __launch_bounds__(256) void a_to_bf16_frag(
    const float* __restrict__ A, unsigned* __restrict__ Afrag) {
  const int g = blockIdx.x * 256 + threadIdx.x;  // 65536 threads
  const int row = g >> 7;                        // [0,512)
  const int col = (g & 127) * 4;                 // 4 consecutive cols
  const float4 f = ((const float4*)A)[g];        // coalesced 16 B read
  const int rt = row >> 4, r15 = row & 15;
  const int kk = col >> 5, qd = (col >> 3) & 3, j = col & 7;  // j in {0,4}
  const unsigned e = (unsigned)(((rt * 16 + kk) * 64 + qd * 16 + r15) * 8 + j);
  uint2 u;
  u.x = pack_bf16_rne2(f.x, f.y);
  u.y = pack_bf16_rne2(f.z, f.w);
  *(uint2*)((unsigned short*)Afrag + e) = u;     // aligned 8 B store
}

// ---------------- DMA-pipelined streaming path (batch == 512) --------------
// Per step per wave: 16 chunks; chunk cc = {4 row-tiles x kk=cc}. Each chunk
// is 4 global_load_lds_dwordx4 (4 KB) into ring slot cc&3. Issue-ahead
// distance 3 chunks -> vmcnt(8) waits exactly chunk cc. Compute: 1 bf
// ds_read_b128 + 4 af ds_read_b128 + 4 MFMAs. D is a single 16 KB LDS buffer
// (all waves read all of it every step; publish after a read-fence barrier).
// Chebyshev math is bitwise identical to r14/r15 (same rounding and order).
__global__ __launch_bounds__(kThreads) void cheb_stream(
    const float* __restrict__ x,    // [B, D]
    const float* __restrict__ t,    // [B]
    const float* __restrict__ mu,   // [D]
    const unsigned short* __restrict__ Af,  // [D*D] bf16 fragment-ordered
    float* __restrict__ out) {      // [B, D]
  const int c0 = blockIdx.x * kCPB;
  const int tid = threadIdx.x;
  const int wave = tid >> 6;        // 0..7
  const int lane = tid & 63;
  const int quad = lane >> 4;
  const int lc = lane & 15;
  const int c = c0 + lc;            // this thread's batch column

  // LDS: A ring 8 waves x 4 slots x 4 KB = 128 KB + D 16 KB = 144 KB
  // -> 1 block/CU guaranteed (2x144 > 160).
  __shared__ alignas(16) unsigned short Abuf[8 * 4 * kChunkShorts];
  __shared__ alignas(16) unsigned short Ds[kFragElems];

  // --- per-column Chebyshev scalars (registers) ---
  const float tb = t[c];
  const float Bt = (kBetaMax - kBetaMin) / (2.0f * kTMax) * tb * tb + kBetaMin * tb;
  const float s_c = expm1f(Bt);
  const float eh = expf(0.5f * Bt);
  const float oscale = -eh * sqrtf(1.0f - expf(-Bt));
  const float theta = 0.5f * (kLamMin + kLamMax) + s_c;
  const float two_sig1 = 2.0f * theta / kDelta;
  const float c2base = 2.0f / kDelta;
  float rho_prev = kDelta / theta;  // 1/sigma1

  // --- state init + publish D_1 into Ds ---
  float R[kRTpW][4], Dv[kRTpW][4], Y[kRTpW][4];
  {
    const float inv_theta = 1.0f / theta;
#pragma unroll
    for (int r = 0; r < kRTpW; ++r) {
      const int i0r = (wave * kRTpW + r) * 16 + quad * 4;  // 4 consecutive rows
      const float4 xv = *(const float4*)(x + (size_t)c * kD + i0r);
      const float4 mu4 = *(const float4*)(mu + i0r);
      const float b0 = eh * xv.x - mu4.x;
      const float b1 = eh * xv.y - mu4.y;
      const float b2 = eh * xv.z - mu4.z;
      const float b3 = eh * xv.w - mu4.w;
      R[r][0] = b0; R[r][1] = b1; R[r][2] = b2; R[r][3] = b3;
      Dv[r][0] = b0 * inv_theta; Dv[r][1] = b1 * inv_theta;
      Dv[r][2] = b2 * inv_theta; Dv[r][3] = b3 * inv_theta;
      Y[r][0] = Dv[r][0]; Y[r][1] = Dv[r][1];
      Y[r][2] = Dv[r][2]; Y[r][3] = Dv[r][3];
      // D fragment slot; i0r%4==0 -> one aligned 8 B write.
      const int db = ((i0r >> 5) * 64 + ((i0r >> 3) & 3) * 16 + lc) * 8 + (i0r & 7);
      uint2 u;
      u.x = pack_bf16_rne2(Dv[r][0], Dv[r][1]);
      u.y = pack_bf16_rne2(Dv[r][2], Dv[r][3]);
      *(uint2*)&Ds[db] = u;
    }
  }

  // Drain init global loads (x/mu/t) so vmcnt counts ONLY A-DMAs below.
  VMCNT(0);
  __builtin_amdgcn_sched_barrier(0);

  unsigned short* const awbase = Abuf + wave * (4 * kChunkShorts);
  // chunk kk piece r: global elem (wave*64 + r*16 + kk)*512 + lane*8
  auto issue_chunk = [&](int kk, int slot) {
    unsigned short* lb = awbase + slot * kChunkShorts;
    const unsigned short* gb = Af + (size_t)(wave * 64 + kk) * 512 + lane * 8;
#pragma unroll
    for (int r = 0; r < 4; ++r)
      gld16(gb + (size_t)r * (16 * 512), lb + r * 512);
  };

  // Prologue DMAs for step 1 (latency overlaps the barrier).
  issue_chunk(0, 0);
  issue_chunk(1, 1);
  issue_chunk(2, 2);
  SBAR();  // D_1 visible to all waves; DMAs stay in flight

  auto do_step = [&](auto lastc) {
    constexpr bool LAST = decltype(lastc)::value;
    float4v acc[kRTpW];
#pragma unroll
    for (int r = 0; r < kRTpW; ++r) acc[r] = (float4v){0.f, 0.f, 0.f, 0.f};

#pragma unroll
    for (int cc = 0; cc < 16; ++cc) {
      // wait: chunk cc landed (issue-ahead keeps 12 DMAs outstanding)
      if (LAST && cc == 15) { VMCNT(0); }
      else if (LAST && cc == 14) { VMCNT(4); }
      else { VMCNT(8); }
      __builtin_amdgcn_sched_barrier(0);  // pin wait; no cross-chunk hoist
      LGKM0();  // ring-slot WAR guard: prior reads of slot (cc+3)&3 retired
      // issue-ahead: chunk cc+3; for non-last steps wrap into next step's
      // chunks 0..2 (A is step-invariant -> identical addresses).
      if (!LAST) {
        issue_chunk((cc + 3) & 15, (cc + 3) & 3);
      } else if (cc < 13) {
        issue_chunk(cc + 3, (cc + 3) & 3);
      }
      // compute chunk cc
      const short8 bfv = *(const short8*)(Ds + (size_t)(cc * 64 + lane) * 8);
      const unsigned short* sb = awbase + (cc & 3) * kChunkShorts + lane * 8;
#pragma unroll
      for (int r = 0; r < kRTpW; ++r) {
        const short8 afv = *(const short8*)(sb + r * 512);
        acc[r] = __builtin_amdgcn_mfma_f32_16x16x32_bf16(afv, bfv, acc[r], 0, 0, 0);
      }
    }

    // ---- Chebyshev recurrence (exact fp32 diagonal term s_c * D) ----
    const float rho_new = 1.0f / (two_sig1 - rho_prev);
    const float cc1 = rho_new * rho_prev;
    const float cc2 = rho_new * c2base;
#pragma unroll
    for (int r = 0; r < kRTpW; ++r)
#pragma unroll
      for (int m = 0; m < 4; ++m) {
        const float v = acc[r][m] + s_c * Dv[r][m];
        R[r][m] -= v;
        Dv[r][m] = fmaf(cc1, Dv[r][m], cc2 * R[r][m]);
        Y[r][m] += Dv[r][m];
      }
    rho_prev = rho_new;

    if (!LAST) {
      SBAR();  // all waves finished READING Ds (single-buffer WAR fence)
#pragma unroll
      for (int r = 0; r < kRTpW; ++r) {
        const int i0r = (wave * kRTpW + r) * 16 + quad * 4;
        const int db = ((i0r >> 5) * 64 + ((i0r >> 3) & 3) * 16 + lc) * 8 + (i0r & 7);
        uint2 u;
        u.x = pack_bf16_rne2(Dv[r][0], Dv[r][1]);
        u.y = pack_bf16_rne2(Dv[r][2], Dv[r][3]);
        *(uint2*)&Ds[db] = u;
      }
      SBAR();  // new D visible
    } else {
#pragma unroll
      for (int r = 0; r < kRTpW; ++r) {
        const int i0r = (wave * kRTpW + r) * 16 + quad * 4;
        float4 o;
        o.x = oscale * Y[r][0];
        o.y = oscale * Y[r][1];
        o.z = oscale * Y[r][2];
        o.w = oscale * Y[r][3];
        *(float4*)(out + (size_t)c * kD + i0r) = o;
      }
    }
  };

  do_step(SF{});  // k=1
  do_step(SF{});  // k=2
  do_step(SF{});  // k=3
  do_step(ST{});  // k=4 (kSteps)
}

// ---------------- Fallback path (r6 kernel, any batch) ----------------
__global__ __launch_bounds__(256) void a_to_bf16(
    const float* __restrict__ A, unsigned* __restrict__ Abf) {
  const int i = blockIdx.x * 256 + threadIdx.x;
  const float4 f = ((const float4*)A)[i];
  uint2 u;
  u.x = pack_bf16_rne2(f.x, f.y);
  u.y = pack_bf16_rne2(f.z, f.w);
  ((uint2*)Abf)[i] = u;
}

namespace {
constexpr int fGroups = 8;
constexpr int fTPG = 128;
constexpr int fThreads = fGroups * fTPG;
constexpr int fRowsG = kD / fGroups;
constexpr int fG = 2;
constexpr int fDeg = 8;
constexpr int fRows = 8;
}

__global__ __launch_bounds__(fThreads) void vp_sde_cheb_fb(
    const float* __restrict__ x, const float* __restrict__ t,
    const float* __restrict__ mu, const uint2* __restrict__ Abf,
    float* __restrict__ out, int batch) {
  const int b0 = blockIdx.x * fG;
  const int tid = threadIdx.x;
  const int grp = tid >> 7;
  const int tl = tid & (fTPG - 1);
  const int d0 = 4 * tl;
  const int jbase = grp * fRowsG;

  __shared__ alignas(16) float d_sh[fG][kD];
  __shared__ alignas(16) float red_sh[fGroups - 1][fG][kD];

  float s[fG], two_sig1[fG], rho_prev[fG], oscale[fG];
  bool vld[fG];
  float4 y[fG], r[fG], dv[fG];
  const float two_over_delta = 2.0f / kDelta;

  uint2 buf0[fRows], buf1[fRows];
#pragma unroll
  for (int rr = 0; rr < fRows; ++rr)
    buf0[rr] = Abf[(size_t)(jbase + rr) * (kD / 4) + tl];

#pragma unroll
  for (int g = 0; g < fG; ++g) {
    const int b = b0 + g;
    vld[g] = (b < batch);
    const float tb = vld[g] ? t[b] : 1.0f;
    const float Bt = (kBetaMax - kBetaMin) / (2.0f * kTMax) * tb * tb + kBetaMin * tb;
    const float sg = expm1f(Bt);
    const float eh = expf(0.5f * Bt);
    s[g] = sg;
    oscale[g] = -eh * sqrtf(1.0f - expf(-Bt));
    const float theta = 0.5f * (kLamMin + kLamMax) + sg;
    const float sig1 = theta / kDelta;
    two_sig1[g] = 2.0f * sig1;
    rho_prev[g] = 1.0f / sig1;

    if (grp == 0) {
      float4 rv = {0.f, 0.f, 0.f, 0.f};
      if (vld[g]) {
        const float4 xv = *(const float4*)&x[(size_t)b * kD + d0];
        const float4 mu4 = *(const float4*)&mu[d0];
        rv.x = eh * xv.x - mu4.x;
        rv.y = eh * xv.y - mu4.y;
        rv.z = eh * xv.z - mu4.z;
        rv.w = eh * xv.w - mu4.w;
      }
      r[g] = rv;
      const float it = 1.0f / theta;
      dv[g].x = rv.x * it; dv[g].y = rv.y * it;
      dv[g].z = rv.z * it; dv[g].w = rv.w * it;
      y[g] = dv[g];
      *(float4*)&d_sh[g][d0] = dv[g];
    }
  }
  __syncthreads();

  for (int k = 1; k < fDeg; ++k) {
    float4 acc[fG];
#pragma unroll
    for (int g = 0; g < fG; ++g) acc[g] = {0.f, 0.f, 0.f, 0.f};

    auto stage = [&](uint2 (&cons)[fRows], uint2 (&ld)[fRows], int jc, int jl) {
#pragma unroll
      for (int rr = 0; rr < fRows; ++rr)
        ld[rr] = Abf[(size_t)(jbase + ((jl + rr) & (fRowsG - 1))) * (kD / 4) + tl];
      float4 pv[fG][fRows / 4];
#pragma unroll
      for (int g = 0; g < fG; ++g)
#pragma unroll
        for (int q = 0; q < fRows / 4; ++q)
          pv[g][q] = *(const float4*)&d_sh[g][jbase + jc + 4 * q];
#pragma unroll
      for (int q = 0; q < fRows / 4; ++q)
#pragma unroll
        for (int cc = 0; cc < 4; ++cc) {
          const uint2 u = cons[4 * q + cc];
          const float fa = __uint_as_float(u.x << 16);
          const float fb = __uint_as_float(u.x & 0xFFFF0000u);
          const float fc = __uint_as_float(u.y << 16);
          const float fd = __uint_as_float(u.y & 0xFFFF0000u);
#pragma unroll
          for (int g = 0; g < fG; ++g) {
            const float pj = (cc == 0) ? pv[g][q].x
                           : (cc == 1) ? pv[g][q].y
                           : (cc == 2) ? pv[g][q].z
                                       : pv[g][q].w;
            acc[g].x = fmaf(fa, pj, acc[g].x);
            acc[g].y = fmaf(fb, pj, acc[g].y);
            acc[g].z = fmaf(fc, pj, acc[g].z);
            acc[g].w = fmaf(fd, pj, acc[g].w);
          }
        }
    };

    int j = 0;
#pragma unroll 1
    for (int i = 0; i < fRowsG / (2 * fRows); ++i, j += 2 * fRows) {
      stage(buf0, buf1, j, j + fRows);
      stage(buf1, buf0, j + fRows, j + 2 * fRows);
    }

    if (grp != 0) {
#pragma unroll
      for (int g = 0; g < fG; ++g)
        *(float4*)&red_sh[grp - 1][g][d0] = acc[g];
    }
    __syncthreads();

    if (grp == 0) {
#pragma unroll
      for (int g = 0; g < fG; ++g) {
        float4 v = acc[g];
#pragma unroll
        for (int q = 0; q < fGroups - 1; ++q) {
          const float4 p = *(const float4*)&red_sh[q][g][d0];
          v.x += p.x; v.y += p.y; v.z += p.z; v.w += p.w;
        }
        v.x = fmaf(s[g], dv[g].x, v.x);
        v.y = fmaf(s[g], dv[g].y, v.y);
        v.z = fmaf(s[g], dv[g].z, v.z);
        v.w = fmaf(s[g], dv[g].w, v.w);
        r[g].x -= v.x; r[g].y -= v.y; r[g].z -= v.z; r[g].w -= v.w;
        const float rho = 1.0f / (two_sig1[g] - rho_prev[g]);
        const float c1 = rho * rho_prev[g];
        const float c2 = rho * two_over_delta;
        dv[g].x = fmaf(c1, dv[g].x, c2 * r[g].x);
        dv[g].y = fmaf(c1, dv[g].y, c2 * r[g].y);
        dv[g].z = fmaf(c1, dv[g].z, c2 * r[g].z);
        dv[g].w = fmaf(c1, dv[g].w, c2 * r[g].w);
        y[g].x += dv[g].x; y[g].y += dv[g].y;
        y[g].z += dv[g].z; y[g].w += dv[g].w;
        rho_prev[g] = rho;
        *(float4*)&d_sh[g][d0] = dv[g];
      }
    }
    __syncthreads();
  }

  if (grp == 0) {
#pragma unroll
    for (int g = 0; g < fG; ++g) {
      if (vld[g]) {
        float4 o;
        o.x = oscale[g] * y[g].x;
        o.y = oscale[g] * y[g].y;
        o.z = oscale[g] * y[g].z;
        o.w = oscale[g] * y[g].w;
        *(float4*)&out[(size_t)(b0 + g) * kD + d0] = o;
      }
    }
  }
}

extern "C" void kernel_launch(void* const* d_in, const int* in_sizes, int n_in,
                              void* d_out, int out_size, void* d_ws, size_t ws_size,
                              hipStream_t stream) {
  const float* x  = (const float*)d_in[0];   // [B, D] fp32
  const float* t  = (const float*)d_in[1];   // [B]    fp32
  const float* mu = (const float*)d_in[2];   // [D]    fp32
  const float* A  = (const float*)d_in[3];   // [D, D] fp32 SPD
  float* out = (float*)d_out;
  const int batch = in_sizes[1];

  char* ws = (char*)d_ws;

  if (batch == kD && ws_size >= 512 * 1024) {
    unsigned short* Af = (unsigned short*)ws;  // 512 KB fragment-ordered bf16 A
    a_to_bf16_frag<<<kD * kD / 4 / 256, 256, 0, stream>>>(A, (unsigned*)Af);
    cheb_stream<<<kBlocks, kThreads, 0, stream>>>(x, t, mu, Af, out);
  } else {
    unsigned* Abf = (unsigned*)d_ws;
    a_to_bf16<<<(kD * kD / 4 + 255) / 256, 256, 0, stream>>>(A, Abf);
    const int blocks = (batch + fG - 1) / fG;
    vp_sde_cheb_fb<<<blocks, fThreads, 0, stream>>>(
        x, t, mu, (const uint2*)Abf, out, batch);
  }
}

// Round 13
// 73.018 us; speedup vs baseline: 1.1106x; 1.1106x over previous
//
#include <hip/hip_runtime.h>
#include <math.h>

namespace {
constexpr int kD = 512;
constexpr float kBetaMin = 0.1f;
constexpr float kBetaMax = 20.0f;
constexpr float kTMax = 1.0f;
// Spectrum of A = M M^T / D + I: lambda_min >= 1 (Wishart PSD),
// lambda_max ~ 4.96 (MP edge 4 + I + TW fluctuation). Containing bounds:
constexpr float kLamMin = 1.0f;
constexpr float kLamMax = 5.2f;
constexpr float kDelta = (kLamMax - kLamMin) * 0.5f;
// kSteps = matvec count. k=4 analytic truncation ~0.03-0.045 vs threshold
// 0.089; measured absmax sits at the bf16 floor (0.0156).
constexpr int kSteps = 4;

// r18: back to the r14 A-in-LDS structure (streaming r15/r17 measured 79.6/81.1
// -> per-CU L2-port bandwidth floor ~14us; counted-vmcnt didn't move it, so
// the family is capped; r14's 72.1 with A resident in LDS is the better base).
// r18 tightens r14's measured-dominant LLC exchange chain:
//  (1) per-member FLAG stores replace the 8-way serialized atomic counter
//      (tid0 stores flag=k; threads 0..7 poll one member each, monotonic
//      "flag >= k" exit) -- removes ~8 serialized LLC RMWs per step,
//  (2) one fewer __syncthreads per step (3 vs 4),
//  (3) s_sleep(1) poll quantum (was 2),
//  (4) LDS padded to 82 KB -> 1 block/CU (dedicated port for gather/stage).
// Compute/rounding/accumulation order bit-identical to r14.
constexpr int kGroupsC = 32;     // independent groups (16 batch-columns each)
constexpr int kMembers = 8;      // blocks per group (64 A-rows each)
constexpr int kCPG = 16;         // columns per group
constexpr int kRowsB = 64;       // A-rows per block (held in LDS)
constexpr int kBarStride = 32;   // uints per flag -> own 128 B line
constexpr int kFragElems = kCPG * kD;   // 8192 bf16 = 16 KB per group D-block

typedef __attribute__((ext_vector_type(8))) short short8;   // 8 bf16
typedef __attribute__((ext_vector_type(4))) float float4v;  // 4 fp32 acc
}

__device__ inline unsigned short bf16_rne(float f) {
  unsigned u = __float_as_uint(f);
  u = (u + 0x7FFFu + ((u >> 16) & 1u)) >> 16;
  return (unsigned short)u;
}

__device__ inline unsigned pack_bf16_rne2(float a, float b) {
  unsigned ua = __float_as_uint(a), ub = __float_as_uint(b);
  ua = (ua + 0x7FFFu + ((ua >> 16) & 1u)) >> 16;
  ub = (ub + 0x7FFFu + ((ub >> 16) & 1u)) >> 16;
  return ua | (ub << 16);
}

// Coherence-bypassing 8 B accessors (relaxed agent-scope atomics ->
// global_{load,store}_dwordx2 sc0 sc1: through the non-coherent XCD L2 to the
// Infinity Cache — r10/r11-proven in the prior session).
__device__ inline void store8_agent(void* p, unsigned lo, unsigned hi) {
  const unsigned long long v = (unsigned long long)lo | ((unsigned long long)hi << 32);
  __hip_atomic_store((unsigned long long*)p, v, __ATOMIC_RELAXED,
                     __HIP_MEMORY_SCOPE_AGENT);
}
__device__ inline unsigned long long load8_agent(const void* p) {
  return __hip_atomic_load((const unsigned long long*)p, __ATOMIC_RELAXED,
                           __HIP_MEMORY_SCOPE_AGENT);
}

// Prologue (main path): A fp32 -> bf16 row-major into ws AND zero the 32 KB
// flag region (per-iteration reset -> immune to workspace poison semantics).
// Kernel-boundary release makes both visible to the main kernel.
__global__ __launch_bounds__(256) void a_to_bf16_z(
    const float* __restrict__ A, unsigned* __restrict__ Abf,
    unsigned* __restrict__ flags) {
  const int i = blockIdx.x * 256 + threadIdx.x;
  const float4 f = ((const float4*)A)[i];
  uint2 u;
  u.x = pack_bf16_rne2(f.x, f.y);
  u.y = pack_bf16_rne2(f.z, f.w);
  ((uint2*)Abf)[i] = u;
  if (blockIdx.x == 0) {
#pragma unroll
    for (int q = 0; q < 32; ++q)
      flags[q * 256 + threadIdx.x] = 0u;   // 8192 uints = 256 flags x 32 stride
  }
}

// ---------------- Fused persistent-chain path (batch == 512) ----------------
// 256 blocks = 32 groups x 8 members. Group g owns batch columns [16g,16g+16);
// member m owns A rows [64m,64m+64) (bf16 in LDS, MFMA-fragment order).
// Dt in global is PER-GROUP FRAGMENT-ORDERED (16 KB contiguous per group).
// Step: spin on 8 member flags (>= k) -> gather 16 KB to LDS (one latency
// exposure) -> stride-1 ds_read_b128 -> 16 MFMAs/wave -> recurrence ->
// publish 8 B fragment -> drain -> flag=k+1.
__global__ __launch_bounds__(256) void cheb_fused(
    const float* __restrict__ x,    // [B, D]
    const float* __restrict__ t,    // [B]
    const float* __restrict__ mu,   // [D]
    const unsigned short* __restrict__ Abf,  // [D, D] bf16 row-major
    float* __restrict__ out,        // [B, D]
    unsigned short* __restrict__ Dt0,   // fragment-ordered ping (32 x 16 KB)
    unsigned short* __restrict__ Dt1,   // fragment-ordered pong
    unsigned* __restrict__ flags) {     // [256*kBarStride] zeroed by prologue
  const int group = blockIdx.x & (kGroupsC - 1);
  const int member = blockIdx.x >> 5;
  const int c0 = group * kCPG;
  const int i0 = member * kRowsB;
  const int tid = threadIdx.x;
  const int wave = tid >> 6;
  const int lane = tid & 63;
  const int quad = lane >> 4;
  const int lc = lane & 15;
  const int c = c0 + lc;                    // this thread's batch column
  const int ibase = i0 + wave * 16 + quad * 4;  // 4 consecutive k (=row) indices

  // Producer fragment address: slot = (k>>5)*64 + ((k>>3)&3)*16 + col,
  // elem = slot*8 + (k&7). Thread's k=ibase..ibase+3 -> one aligned 8 B piece.
  const size_t fragOff = (size_t)group * kFragElems +
      (size_t)(((ibase >> 5) * 64 + ((ibase >> 3) & 3) * 16 + lc) * 8 + (ibase & 7));

  // LDS: A slab 64 KB (fragment-ordered) + D staging 16 KB + 2 KB pad = 82 KB
  // -> 1 block/CU (2x82 > 160): dedicated L2 port per block, no co-resident
  // straggler interleaving the latency chain.
  __shared__ unsigned short As[kRowsB * kD];
  __shared__ unsigned short Ds[kFragElems + 1024];

  // --- per-column Chebyshev scalars (registers) ---
  const float tb = t[c];
  const float Bt = (kBetaMax - kBetaMin) / (2.0f * kTMax) * tb * tb + kBetaMin * tb;
  const float s_c = expm1f(Bt);
  const float eh = expf(0.5f * Bt);
  const float oscale = -eh * sqrtf(1.0f - expf(-Bt));
  const float theta = 0.5f * (kLamMin + kLamMax) + s_c;
  const float two_sig1 = 2.0f * theta / kDelta;
  const float c2base = 2.0f / kDelta;
  float rho_prev = kDelta / theta;          // 1/sigma1

  // --- state init + EARLY publish of D_1 (fragment-ordered 8 B store) ---
  float R[4], Dv[4], Y[4];
  {
    const float inv_theta = 1.0f / theta;
#pragma unroll
    for (int m = 0; m < 4; ++m) {
      const int i = ibase + m;
      const float b = eh * x[(size_t)c * kD + i] - mu[i];
      R[m] = b;
      Dv[m] = b * inv_theta;
      Y[m] = Dv[m];
    }
    store8_agent(Dt0 + fragOff,
                 (unsigned)bf16_rne(Dv[0]) | ((unsigned)bf16_rne(Dv[1]) << 16),
                 (unsigned)bf16_rne(Dv[2]) | ((unsigned)bf16_rne(Dv[3]) << 16));
  }

  // --- stage A slab (already bf16): 16 B coalesced reads, fragment reorder ---
  for (int idx = tid; idx < kRowsB * (kD / 8); idx += 256) {
    const int row = idx >> 6;              // local row 0..63
    const int col = (idx & 63) * 8;        // j-run start (j=0)
    const uint4 v = *(const uint4*)(Abf + (size_t)(i0 + row) * kD + col);
    const int w = row >> 4, l = row & 15;
    const int kk = col >> 5, qd = (col >> 3) & 3;
    *(uint4*)&As[(w * 1024 + kk * 64 + qd * 16 + l) * 8] = v;
  }

  unsigned* const myFlag = flags + ((group << 3) + member) * kBarStride;
  __syncthreads();   // drains vmcnt: D_1 publish + A staging complete
  if (tid == 0)
    __hip_atomic_store(myFlag, 1u, __ATOMIC_RELAXED, __HIP_MEMORY_SCOPE_AGENT);

  const unsigned short* groupIn0 = Dt0 + (size_t)group * kFragElems;
  const unsigned short* groupIn1 = Dt1 + (size_t)group * kFragElems;

  for (int k = 1; k <= kSteps; ++k) {
    // ---- flag wait: threads 0..7 each poll one member's flag (>= k) ----
    if (tid < kMembers) {
      const unsigned* fl = flags + ((group << 3) + tid) * kBarStride;
      while (__hip_atomic_load(fl, __ATOMIC_RELAXED, __HIP_MEMORY_SCOPE_AGENT) <
             (unsigned)k)
        __builtin_amdgcn_s_sleep(1);
    }
    __syncthreads();

    // ---- cooperative gather: group's 16 KB D-block -> LDS (coalesced) ----
    const unsigned short* gin = (k & 1) ? groupIn0 : groupIn1;
    unsigned long long stg[8];
#pragma unroll
    for (int i = 0; i < 8; ++i)
      stg[i] = load8_agent((const char*)gin + (size_t)i * 2048 + (size_t)tid * 8);
#pragma unroll
    for (int i = 0; i < 8; ++i)
      *(unsigned long long*)((char*)Ds + (size_t)i * 2048 + (size_t)tid * 8) = stg[i];
    __syncthreads();

    // ---- V-tile = A_slab x D (K = 512): B-frags from LDS, stride-1 b128 ----
    float4v acc = {0.f, 0.f, 0.f, 0.f};
    const unsigned short* afp = As + (size_t)(wave * 1024 + lane) * 8;
#pragma unroll
    for (int kk = 0; kk < kD / 32; ++kk) {
      const short8 af = *(const short8*)(afp + (size_t)kk * 64 * 8);
      const short8 bf = *(const short8*)(Ds + (size_t)(kk * 64 + lane) * 8);
      acc = __builtin_amdgcn_mfma_f32_16x16x32_bf16(af, bf, acc, 0, 0, 0);
    }

    // ---- Chebyshev recurrence (exact fp32 diagonal term s_c * D) ----
    const float rho_new = 1.0f / (two_sig1 - rho_prev);
    const float cc1 = rho_new * rho_prev;
    const float cc2 = rho_new * c2base;
#pragma unroll
    for (int m = 0; m < 4; ++m) {
      const float v = acc[m] + s_c * Dv[m];
      R[m] -= v;
      Dv[m] = fmaf(cc1, Dv[m], cc2 * R[m]);
      Y[m] += Dv[m];
    }
    rho_prev = rho_new;

    if (k < kSteps) {
      unsigned short* gout = ((k & 1) ? Dt1 : Dt0);
      store8_agent(gout + fragOff,
                   (unsigned)bf16_rne(Dv[0]) | ((unsigned)bf16_rne(Dv[1]) << 16),
                   (unsigned)bf16_rne(Dv[2]) | ((unsigned)bf16_rne(Dv[3]) << 16));
      __syncthreads();   // drains vmcnt: whole block's D_{k+1} publish complete
      if (tid == 0)
        __hip_atomic_store(myFlag, (unsigned)(k + 1), __ATOMIC_RELAXED,
                           __HIP_MEMORY_SCOPE_AGENT);
    } else {
      float4 o;
      o.x = oscale * Y[0];
      o.y = oscale * Y[1];
      o.z = oscale * Y[2];
      o.w = oscale * Y[3];
      *(float4*)(out + (size_t)c * kD + ibase) = o;
    }
  }
}

// ---------------- Fallback path (r6 kernel, any batch) ----------------
__global__ __launch_bounds__(256) void a_to_bf16(
    const float* __restrict__ A, unsigned* __restrict__ Abf) {
  const int i = blockIdx.x * 256 + threadIdx.x;
  const float4 f = ((const float4*)A)[i];
  uint2 u;
  u.x = pack_bf16_rne2(f.x, f.y);
  u.y = pack_bf16_rne2(f.z, f.w);
  ((uint2*)Abf)[i] = u;
}

namespace {
constexpr int fGroups = 8;
constexpr int fTPG = 128;
constexpr int fThreads = fGroups * fTPG;
constexpr int fRowsG = kD / fGroups;
constexpr int fG = 2;
constexpr int fDeg = 8;
constexpr int fRows = 8;
}

__global__ __launch_bounds__(fThreads) void vp_sde_cheb_fb(
    const float* __restrict__ x, const float* __restrict__ t,
    const float* __restrict__ mu, const uint2* __restrict__ Abf,
    float* __restrict__ out, int batch) {
  const int b0 = blockIdx.x * fG;
  const int tid = threadIdx.x;
  const int grp = tid >> 7;
  const int tl = tid & (fTPG - 1);
  const int d0 = 4 * tl;
  const int jbase = grp * fRowsG;

  __shared__ alignas(16) float d_sh[fG][kD];
  __shared__ alignas(16) float red_sh[fGroups - 1][fG][kD];

  float s[fG], two_sig1[fG], rho_prev[fG], oscale[fG];
  bool vld[fG];
  float4 y[fG], r[fG], dv[fG];
  const float two_over_delta = 2.0f / kDelta;

  uint2 buf0[fRows], buf1[fRows];
#pragma unroll
  for (int rr = 0; rr < fRows; ++rr)
    buf0[rr] = Abf[(size_t)(jbase + rr) * (kD / 4) + tl];

#pragma unroll
  for (int g = 0; g < fG; ++g) {
    const int b = b0 + g;
    vld[g] = (b < batch);
    const float tb = vld[g] ? t[b] : 1.0f;
    const float Bt = (kBetaMax - kBetaMin) / (2.0f * kTMax) * tb * tb + kBetaMin * tb;
    const float sg = expm1f(Bt);
    const float eh = expf(0.5f * Bt);
    s[g] = sg;
    oscale[g] = -eh * sqrtf(1.0f - expf(-Bt));
    const float theta = 0.5f * (kLamMin + kLamMax) + sg;
    const float sig1 = theta / kDelta;
    two_sig1[g] = 2.0f * sig1;
    rho_prev[g] = 1.0f / sig1;

    if (grp == 0) {
      float4 rv = {0.f, 0.f, 0.f, 0.f};
      if (vld[g]) {
        const float4 xv = *(const float4*)&x[(size_t)b * kD + d0];
        const float4 mu4 = *(const float4*)&mu[d0];
        rv.x = eh * xv.x - mu4.x;
        rv.y = eh * xv.y - mu4.y;
        rv.z = eh * xv.z - mu4.z;
        rv.w = eh * xv.w - mu4.w;
      }
      r[g] = rv;
      const float it = 1.0f / theta;
      dv[g].x = rv.x * it; dv[g].y = rv.y * it;
      dv[g].z = rv.z * it; dv[g].w = rv.w * it;
      y[g] = dv[g];
      *(float4*)&d_sh[g][d0] = dv[g];
    }
  }
  __syncthreads();

  for (int k = 1; k < fDeg; ++k) {
    float4 acc[fG];
#pragma unroll
    for (int g = 0; g < fG; ++g) acc[g] = {0.f, 0.f, 0.f, 0.f};

    auto stage = [&](uint2 (&cons)[fRows], uint2 (&ld)[fRows], int jc, int jl) {
#pragma unroll
      for (int rr = 0; rr < fRows; ++rr)
        ld[rr] = Abf[(size_t)(jbase + ((jl + rr) & (fRowsG - 1))) * (kD / 4) + tl];
      float4 pv[fG][fRows / 4];
#pragma unroll
      for (int g = 0; g < fG; ++g)
#pragma unroll
        for (int q = 0; q < fRows / 4; ++q)
          pv[g][q] = *(const float4*)&d_sh[g][jbase + jc + 4 * q];
#pragma unroll
      for (int q = 0; q < fRows / 4; ++q)
#pragma unroll
        for (int cc = 0; cc < 4; ++cc) {
          const uint2 u = cons[4 * q + cc];
          const float fa = __uint_as_float(u.x << 16);
          const float fb = __uint_as_float(u.x & 0xFFFF0000u);
          const float fc = __uint_as_float(u.y << 16);
          const float fd = __uint_as_float(u.y & 0xFFFF0000u);
#pragma unroll
          for (int g = 0; g < fG; ++g) {
            const float pj = (cc == 0) ? pv[g][q].x
                           : (cc == 1) ? pv[g][q].y
                           : (cc == 2) ? pv[g][q].z
                                       : pv[g][q].w;
            acc[g].x = fmaf(fa, pj, acc[g].x);
            acc[g].y = fmaf(fb, pj, acc[g].y);
            acc[g].z = fmaf(fc, pj, acc[g].z);
            acc[g].w = fmaf(fd, pj, acc[g].w);
          }
        }
    };

    int j = 0;
#pragma unroll 1
    for (int i = 0; i < fRowsG / (2 * fRows); ++i, j += 2 * fRows) {
      stage(buf0, buf1, j, j + fRows);
      stage(buf1, buf0, j + fRows, j + 2 * fRows);
    }

    if (grp != 0) {
#pragma unroll
      for (int g = 0; g < fG; ++g)
        *(float4*)&red_sh[grp - 1][g][d0] = acc[g];
    }
    __syncthreads();

    if (grp == 0) {
#pragma unroll
      for (int g = 0; g < fG; ++g) {
        float4 v = acc[g];
#pragma unroll
        for (int q = 0; q < fGroups - 1; ++q) {
          const float4 p = *(const float4*)&red_sh[q][g][d0];
          v.x += p.x; v.y += p.y; v.z += p.z; v.w += p.w;
        }
        v.x = fmaf(s[g], dv[g].x, v.x);
        v.y = fmaf(s[g], dv[g].y, v.y);
        v.z = fmaf(s[g], dv[g].z, v.z);
        v.w = fmaf(s[g], dv[g].w, v.w);
        r[g].x -= v.x; r[g].y -= v.y; r[g].z -= v.z; r[g].w -= v.w;
        const float rho = 1.0f / (two_sig1[g] - rho_prev[g]);
        const float c1 = rho * rho_prev[g];
        const float c2 = rho * two_over_delta;
        dv[g].x = fmaf(c1, dv[g].x, c2 * r[g].x);
        dv[g].y = fmaf(c1, dv[g].y, c2 * r[g].y);
        dv[g].z = fmaf(c1, dv[g].z, c2 * r[g].z);
        dv[g].w = fmaf(c1, dv[g].w, c2 * r[g].w);
        y[g].x += dv[g].x; y[g].y += dv[g].y;
        y[g].z += dv[g].z; y[g].w += dv[g].w;
        rho_prev[g] = rho;
        *(float4*)&d_sh[g][d0] = dv[g];
      }
    }
    __syncthreads();
  }

  if (grp == 0) {
#pragma unroll
    for (int g = 0; g < fG; ++g) {
      if (vld[g]) {
        float4 o;
        o.x = oscale[g] * y[g].x;
        o.y = oscale[g] * y[g].y;
        o.z = oscale[g] * y[g].z;
        o.w = oscale[g] * y[g].w;
        *(float4*)&out[(size_t)(b0 + g) * kD + d0] = o;
      }
    }
  }
}

extern "C" void kernel_launch(void* const* d_in, const int* in_sizes, int n_in,
                              void* d_out, int out_size, void* d_ws, size_t ws_size,
                              hipStream_t stream) {
  const float* x  = (const float*)d_in[0];   // [B, D] fp32
  const float* t  = (const float*)d_in[1];   // [B]    fp32
  const float* mu = (const float*)d_in[2];   // [D]    fp32
  const float* A  = (const float*)d_in[3];   // [D, D] fp32 SPD
  float* out = (float*)d_out;
  const int batch = in_sizes[1];

  char* ws = (char*)d_ws;
  const size_t flagBytes = 256u * kBarStride * sizeof(unsigned);  // 32 KB
  const size_t need = 1536 * 1024 + flagBytes;

  if (batch == kD && ws_size >= need) {
    unsigned short* Abf = (unsigned short*)(ws);                 // 512 KB bf16 A
    unsigned short* Dt0 = (unsigned short*)(ws + 512 * 1024);    // 512 KB
    unsigned short* Dt1 = (unsigned short*)(ws + 1024 * 1024);   // 512 KB
    unsigned* flags = (unsigned*)(ws + 1536 * 1024);             // 32 KB

    // Prologue: A -> bf16 + zero member flags (per-iteration reset).
    a_to_bf16_z<<<kD * kD / 4 / 256, 256, 0, stream>>>(A, (unsigned*)Abf, flags);
    cheb_fused<<<kGroupsC * kMembers, 256, 0, stream>>>(
        x, t, mu, Abf, out, Dt0, Dt1, flags);
  } else {
    unsigned* Abf = (unsigned*)d_ws;
    a_to_bf16<<<(kD * kD / 4 + 255) / 256, 256, 0, stream>>>(A, Abf);
    const int blocks = (batch + fG - 1) / fG;
    vp_sde_cheb_fb<<<blocks, fThreads, 0, stream>>>(
        x, t, mu, (const uint2*)Abf, out, batch);
  }
}